// Round 5
// baseline (2329.570 us; speedup 1.0000x reference)
//
#include <hip/hip_runtime.h>

#define T_SZ 65536
#define K_SZ 2048
#define D_SZ 256

// numpy pairwise_sum replica for 128 contiguous squared elements.
// numpy: r[0..7] = a[0..7]; for i=8..120 step 8: r[j]+=a[i+j];
//        res = ((r0+r1)+(r2+r3))+((r4+r5)+(r6+r7))
// applied to a[i]^2 with each square rounded BEFORE the add (contract off).
__device__ __forceinline__ float pairwise128_sq(const float* __restrict__ a) {
#pragma clang fp contract(off)
  float r0 = a[0] * a[0], r1 = a[1] * a[1], r2 = a[2] * a[2], r3 = a[3] * a[3];
  float r4 = a[4] * a[4], r5 = a[5] * a[5], r6 = a[6] * a[6], r7 = a[7] * a[7];
#pragma unroll
  for (int i = 8; i < 128; i += 8) {
    r0 += a[i + 0] * a[i + 0];
    r1 += a[i + 1] * a[i + 1];
    r2 += a[i + 2] * a[i + 2];
    r3 += a[i + 3] * a[i + 3];
    r4 += a[i + 4] * a[i + 4];
    r5 += a[i + 5] * a[i + 5];
    r6 += a[i + 6] * a[i + 6];
    r7 += a[i + 7] * a[i + 7];
  }
  return ((r0 + r1) + (r2 + r3)) + ((r4 + r5) + (r6 + r7));
}

// e_sq[k] = numpy-pairwise sum of e[k][:]^2  (n=256 -> 128+128 split)
__global__ void esq_kernel(const float* __restrict__ e, float* __restrict__ esq) {
  int k = blockIdx.x * 64 + threadIdx.x;  // 32 blocks x 64 = 2048
  const float* er = e + (size_t)k * D_SZ;
  esq[k] = pairwise128_sq(er) + pairwise128_sq(er + 128);
}

// Main kernel, BARRIER-FREE: one wave (64 threads) per workgroup.
// Rationale (R4 post-mortem): with 256-thread blocks all 8 waves release from
// __syncthreads together and stall together (VALUBusy 58%, occupancy stuck at
// ~2.2 blocks/CU). A 1-wave workgroup needs NO barrier: LDS staging is
// same-wave (DS ops are in-order per wave; compiler inserts lgkmcnt), so waves
// free-run and self-pipeline (e-prefetch for round n+1 overlaps round n).
//
// Tile: wave = 16 tx x 4 ty; thread tile 8 rows x 8 codes -> 32 rows x 128
// codes per chunk; K split in 2 halves across blocks -> grid 4096 (16 waves/CU
// offered; VGPR cap 170 via launch_bounds(64,3) -> 3 waves/SIMD resident).
// e staged in single-buffer LDS es[128][20] (pitch 80B):
//   writes: 8 x b128/lane/round, 8 words/bank uniform (optimal);
//   reads: 16 distinct codes x 4-way ty-broadcast, 2 words/bank (optimal).
// x: global->register, 16-lane broadcast loads (L1/L2-resident slice).
__global__ __launch_bounds__(64, 3) void vq_argmin_kernel(
    const float* __restrict__ x, const float* __restrict__ e,
    const float* __restrict__ esq_g, float* __restrict__ cand_v,
    int* __restrict__ cand_i) {
  __shared__ __align__(16) float es[128][20];  // 10240 B, single-buffered
  __shared__ float xsq_s[32];

  const int lane = threadIdx.x;
  const int tx = lane & 15;
  const int ty = lane >> 4;
  const int half = blockIdx.x & 1;
  const int rowbase = (blockIdx.x >> 1) * 32;
  const int kbase = half * 1024;

  // x_sq for the block's 32 rows (lanes 0..31), numpy pairwise. Same-wave LDS
  // visibility: read later by all lanes after lgkmcnt, no barrier needed.
  if (lane < 32) {
    const float* xr = x + (size_t)(rowbase + lane) * D_SZ;
    xsq_s[lane] = pairwise128_sq(xr) + pairwise128_sq(xr + 128);
  }

  const float4* x4 = reinterpret_cast<const float4*>(x);
  const float4* e4 = reinterpret_cast<const float4*>(e);

  const int c0 = lane >> 2;  // staging code offset 0..15 (codes 16j + c0)
  const int q0 = lane & 3;   // staging quad

  float4 pe[8];  // e prefetch: 8 float4 = one full round slice per lane

  auto prefetch_e = [&](int round) {
    const int chunk = round >> 4, dstep = round & 15;
    const float4* base =
        e4 + (size_t)(kbase + chunk * 128 + c0) * 64 + dstep * 4 + q0;
#pragma unroll
    for (int j = 0; j < 8; ++j) pe[j] = base[(size_t)j * 16 * 64];
  };

  auto write_es = [&]() {
#pragma unroll
    for (int j = 0; j < 8; ++j)
      *reinterpret_cast<float4*>(&es[16 * j + c0][4 * q0]) = pe[j];
  };

  prefetch_e(0);
  write_es();

  float acc[8][8];
#pragma unroll
  for (int r = 0; r < 8; ++r)
#pragma unroll
    for (int c = 0; c < 8; ++c) acc[r][c] = 0.0f;

  float bestv[8];
  int besti[8];
#pragma unroll
  for (int r = 0; r < 8; ++r) {
    bestv[r] = 3.402823466e38f;
    besti[r] = 0;
  }

  // This thread's 8 rows (8*ty .. 8*ty+7); row pitch = 64 float4s.
  const float4* xrow = x4 + (size_t)(rowbase + 8 * ty) * 64;

#pragma unroll 1
  for (int chunk = 0; chunk < 8; ++chunk) {
#pragma unroll 1
    for (int dstep = 0; dstep < 16; ++dstep) {
      const int round = chunk * 16 + dstep;
      if (round < 127) prefetch_e(round + 1);  // in flight across the round
#pragma unroll 1
      for (int q = 0; q < 4; ++q) {
        // this 4-d group of x (8 rows), broadcast across the 16 tx lanes
        float4 xg[8];
#pragma unroll
        for (int i = 0; i < 8; ++i) xg[i] = xrow[i * 64 + dstep * 4 + q];
#pragma unroll
        for (int c = 0; c < 8; ++c) {
          float4 ev = *reinterpret_cast<const float4*>(&es[16 * c + tx][4 * q]);
#pragma unroll
          for (int r = 0; r < 8; ++r) {
            // d ascending within quad -> global d order 0..255 sequential
            acc[r][c] = __builtin_fmaf(xg[r].x, ev.x, acc[r][c]);
            acc[r][c] = __builtin_fmaf(xg[r].y, ev.y, acc[r][c]);
            acc[r][c] = __builtin_fmaf(xg[r].z, ev.z, acc[r][c]);
            acc[r][c] = __builtin_fmaf(xg[r].w, ev.w, acc[r][c]);
          }
        }
      }
      // Overwrite es with next round's slice. Safe without barrier: all reads
      // above are same-wave and DS ops execute in issue order per wave; the
      // true RAW/WAR dependency on the same buffer keeps compiler order too.
      if (round < 127) write_es();
    }
    // epilogue for this 128-code chunk: dist = (x_sq - 2*cross) + e_sq, argmin
    const int nbase = kbase + chunk * 128;
#pragma unroll
    for (int c = 0; c < 8; ++c) {
      const int k = nbase + 16 * c + tx;  // ascending k within thread
      const float esq = esq_g[k];
#pragma unroll
      for (int r = 0; r < 8; ++r) {
        float xsq = xsq_s[8 * ty + r];      // broadcast LDS read
        float t1 = xsq - 2.0f * acc[r][c];  // 2*acc exact; matches np
        float dist = t1 + esq;
        bool better = dist < bestv[r];  // strict <: lowest k wins ties
        bestv[r] = better ? dist : bestv[r];
        besti[r] = better ? k : besti[r];
        acc[r][c] = 0.0f;
      }
    }
  }

  // fold the 16 tx-lanes per row (lane bits 0..3 = tx); tie-break: lowest index
#pragma unroll
  for (int m = 1; m < 16; m <<= 1) {
#pragma unroll
    for (int r = 0; r < 8; ++r) {
      float ov = __shfl_xor(bestv[r], m, 64);
      int oi = __shfl_xor(besti[r], m, 64);
      bool take = (ov < bestv[r]) || ((ov == bestv[r]) && (oi < besti[r]));
      bestv[r] = take ? ov : bestv[r];
      besti[r] = take ? oi : besti[r];
    }
  }
  if (tx == 0) {
#pragma unroll
    for (int r = 0; r < 8; ++r) {
      cand_v[half * T_SZ + rowbase + 8 * ty + r] = bestv[r];
      cand_i[half * T_SZ + rowbase + 8 * ty + r] = besti[r];
    }
  }
}

// Combine the two K-halves (strict < : half 0 wins ties -> lower index, matching
// np.argmin first-occurrence), then out0 = x + (e[idx] - x) elementwise fp32.
__global__ __launch_bounds__(256) void decode_kernel(
    const float* __restrict__ x, const float* __restrict__ e,
    const float* __restrict__ cand_v, const int* __restrict__ cand_i,
    float* __restrict__ out, float* __restrict__ outIdx) {
  size_t g = (size_t)blockIdx.x * 256 + threadIdx.x;  // float4 index
  size_t t = g >> 6;
  int q = (int)(g & 63);
  float v0 = cand_v[t], v1 = cand_v[T_SZ + t];
  int i0 = cand_i[t], i1 = cand_i[T_SZ + t];
  int idx = (v1 < v0) ? i1 : i0;  // wave-uniform (t uniform across the wave)
  if (q == 0) outIdx[t] = (float)idx;
  const float4* x4 = reinterpret_cast<const float4*>(x);
  const float4* e4 = reinterpret_cast<const float4*>(e);
  float4 xv = x4[t * 64 + q];
  float4 qv = e4[(size_t)idx * 64 + q];
  float4 o;
  o.x = xv.x + (qv.x - xv.x);
  o.y = xv.y + (qv.y - xv.y);
  o.z = xv.z + (qv.z - xv.z);
  o.w = xv.w + (qv.w - xv.w);
  reinterpret_cast<float4*>(out)[g] = o;
}

extern "C" void kernel_launch(void* const* d_in, const int* in_sizes, int n_in,
                              void* d_out, int out_size, void* d_ws, size_t ws_size,
                              hipStream_t stream) {
  const float* x = (const float*)d_in[0];      // (65536, 256) fp32
  const float* e = (const float*)d_in[1];      // (2048, 256) fp32
  float* out = (float*)d_out;                  // [T*D quantized | T indices-as-float]
  float* outIdx = out + (size_t)T_SZ * D_SZ;

  float* esq = (float*)d_ws;                       // 2048 floats
  float* cand_v = esq + K_SZ;                      // 2*T floats
  int* cand_i = (int*)(cand_v + 2 * T_SZ);         // 2*T ints

  esq_kernel<<<K_SZ / 64, 64, 0, stream>>>(e, esq);
  vq_argmin_kernel<<<(T_SZ / 32) * 2, 64, 0, stream>>>(x, e, esq, cand_v, cand_i);
  decode_kernel<<<(T_SZ * (D_SZ / 4)) / 256, 256, 0, stream>>>(x, e, cand_v, cand_i,
                                                               out, outIdx);
}